// Round 3
// baseline (553.409 us; speedup 1.0000x reference)
//
#include <hip/hip_runtime.h>

#define BB 16
#define NN 2048
#define FF 128
#define NEG 0.01f
#define CH 32          // chunks per batch for vector prefix sums
#define CL (NN / CH)   // chunk length = 64

// ---------------------------------------------------------------------------
// K1: Wh = h @ W  (fp32, LDS-tiled), fused f1 = Wh·a1, f2 = Wh·a2
// ---------------------------------------------------------------------------
__global__ __launch_bounds__(256) void k_wh(const float* __restrict__ h,
                                            const float* __restrict__ Wg,
                                            const float* __restrict__ a,
                                            float* __restrict__ Wh,
                                            float* __restrict__ f1,
                                            float* __restrict__ f2) {
    __shared__ float Ws[64 * 128];   // [k][f] half-K tile (32 KB)
    __shared__ float hsT[64 * 36];   // [k][row] transposed h tile, pad 36 (9 KB)

    const int tid  = threadIdx.x;
    const int fg   = tid & 31;        // f-group
    const int slot = tid >> 5;        // row-slot 0..7
    const int f4   = fg * 4;
    const int rowBase = blockIdx.x * 32;

    float acc[4][4];
#pragma unroll
    for (int r = 0; r < 4; ++r)
#pragma unroll
        for (int c = 0; c < 4; ++c) acc[r][c] = 0.f;

    const float4* Wg4 = (const float4*)Wg;
    const float4* hg4 = (const float4*)h;

    for (int kh = 0; kh < 128; kh += 64) {
        __syncthreads();
        for (int idx = tid; idx < 64 * 32; idx += 256) {
            int kk = idx >> 5, ff = idx & 31;
            ((float4*)Ws)[kk * 32 + ff] = Wg4[(size_t)(kh + kk) * 32 + ff];
        }
#pragma unroll
        for (int pass = 0; pass < 2; ++pass) {
            int idx = pass * 256 + tid;            // 0..511
            int kq = idx & 15, row = idx >> 4;     // kq 0..15, row 0..31
            float4 h4 = hg4[(size_t)(rowBase + row) * 32 + (kh >> 2) + kq];
            hsT[(kq * 4 + 0) * 36 + row] = h4.x;
            hsT[(kq * 4 + 1) * 36 + row] = h4.y;
            hsT[(kq * 4 + 2) * 36 + row] = h4.z;
            hsT[(kq * 4 + 3) * 36 + row] = h4.w;
        }
        __syncthreads();
#pragma unroll 8
        for (int kk = 0; kk < 64; ++kk) {
            float4 wv = *(const float4*)&Ws[kk * 128 + f4];
            float4 hv = *(const float4*)&hsT[kk * 36 + slot * 4];
            acc[0][0] += hv.x * wv.x; acc[0][1] += hv.x * wv.y; acc[0][2] += hv.x * wv.z; acc[0][3] += hv.x * wv.w;
            acc[1][0] += hv.y * wv.x; acc[1][1] += hv.y * wv.y; acc[1][2] += hv.y * wv.z; acc[1][3] += hv.y * wv.w;
            acc[2][0] += hv.z * wv.x; acc[2][1] += hv.z * wv.y; acc[2][2] += hv.z * wv.z; acc[2][3] += hv.z * wv.w;
            acc[3][0] += hv.w * wv.x; acc[3][1] += hv.w * wv.y; acc[3][2] += hv.w * wv.z; acc[3][3] += hv.w * wv.w;
        }
    }

    const float4* ag4 = (const float4*)a;
    float4 a1v = ag4[fg];
    float4 a2v = ag4[32 + fg];

#pragma unroll
    for (int r = 0; r < 4; ++r) {
        int row = rowBase + slot * 4 + r;
        float4 o; o.x = acc[r][0]; o.y = acc[r][1]; o.z = acc[r][2]; o.w = acc[r][3];
        *(float4*)&Wh[(size_t)row * 128 + f4] = o;
        float p1 = acc[r][0] * a1v.x + acc[r][1] * a1v.y + acc[r][2] * a1v.z + acc[r][3] * a1v.w;
        float p2 = acc[r][0] * a2v.x + acc[r][1] * a2v.y + acc[r][2] * a2v.z + acc[r][3] * a2v.w;
#pragma unroll
        for (int m = 16; m >= 1; m >>= 1) {
            p1 += __shfl_xor(p1, m);
            p2 += __shfl_xor(p2, m);
        }
        if (fg == 0) { f1[row] = p1; f2[row] = p2; }
    }
}

// ---------------------------------------------------------------------------
// wave-level inclusive scan (width 64)
// ---------------------------------------------------------------------------
__device__ __forceinline__ float wave_incl_scan(float s, int lane) {
#pragma unroll
    for (int m = 1; m <= 32; m <<= 1) {
        float o = __shfl_up(s, m);
        if (lane >= m) s += o;
    }
    return s;
}

#define WAVE_SYNC() do { __builtin_amdgcn_wave_barrier(); asm volatile("" ::: "memory"); } while (0)

// ---------------------------------------------------------------------------
// K2: 32 blocks x 1024 threads.
//  task 0 (blocks 0-15): sort f1 asc -> SF1g; shuffle scans -> PAg (exclusive
//    prefix of exp(0.01*sf1), length N+1) and SAg (suffix of exp(sf1), N+1).
//  task 1 (blocks 16-31): sort (f2,idx) pairs -> SKg, PERM; KIDX[i] =
//    #{t : sf2[t] <= -f1[i]} via LDS binary search.
// ---------------------------------------------------------------------------
__global__ __launch_bounds__(1024) void k_sort2(const float* __restrict__ f1,
                                                const float* __restrict__ f2,
                                                float* __restrict__ SF1g,
                                                float* __restrict__ PAg,
                                                float* __restrict__ SAg,
                                                float* __restrict__ SKg,
                                                int* __restrict__ PERM,
                                                int* __restrict__ KIDX) {
    __shared__ float sKey[NN];
    __shared__ int   sIdx[NN];
    __shared__ float wtot[16];

    const int tid  = threadIdx.x;
    const int lane = tid & 63;
    const int w    = tid >> 6;
    const int b    = blockIdx.x & 15;
    const int task = blockIdx.x >> 4;

    const float* f1b = f1 + b * NN;
    const float* f2b = f2 + b * NN;

    if (task == 0) {
        for (int i = tid; i < NN; i += 1024) sKey[i] = f1b[i];
    } else {
        for (int i = tid; i < NN; i += 1024) { sKey[i] = f2b[i]; sIdx[i] = i; }
    }

    int prevj = 1024;  // force barrier before first phase
    for (int k = 2; k <= NN; k <<= 1) {
        for (int j = k >> 1; j > 0; j >>= 1) {
            if (j >= 128 || prevj >= 128) __syncthreads();
            else WAVE_SYNC();
            int mask = j - 1;
            int i   = ((tid & ~mask) << 1) | (tid & mask);
            int ixj = i | j;
            bool up = ((i & k) == 0);
            float av = sKey[i], bv = sKey[ixj];
            if ((av > bv) == up) {
                sKey[i] = bv; sKey[ixj] = av;
                if (task == 1) { int t2 = sIdx[i]; sIdx[i] = sIdx[ixj]; sIdx[ixj] = t2; }
            }
            prevj = j;
        }
    }
    __syncthreads();

    if (task == 0) {
        for (int i = tid; i < NN; i += 1024) SF1g[b * NN + i] = sKey[i];
        const size_t pbase = (size_t)b * (NN + 1);
        {
            float a0 = expf(NEG * sKey[2 * tid]);
            float a1 = expf(NEG * sKey[2 * tid + 1]);
            float s = a0 + a1;
            float v = wave_incl_scan(s, lane);
            if (lane == 63) wtot[w] = v;
            __syncthreads();
            float off = 0.f;
#pragma unroll
            for (int ww = 0; ww < 16; ++ww) off += (ww < w) ? wtot[ww] : 0.f;
            float excl = off + v - s;
            PAg[pbase + 2 * tid]     = excl;
            PAg[pbase + 2 * tid + 1] = excl + a0;
            if (tid == 1023) PAg[pbase + NN] = off + v;
        }
        __syncthreads();
        {
            float y0 = expf(sKey[NN - 1 - 2 * tid]);
            float y1 = expf(sKey[NN - 2 - 2 * tid]);
            float s = y0 + y1;
            float v = wave_incl_scan(s, lane);
            if (lane == 63) wtot[w] = v;
            __syncthreads();
            float off = 0.f;
#pragma unroll
            for (int ww = 0; ww < 16; ++ww) off += (ww < w) ? wtot[ww] : 0.f;
            SAg[pbase + NN - 1 - 2 * tid] = off + (v - s) + y0;
            SAg[pbase + NN - 2 - 2 * tid] = off + v;
            if (tid == 0) SAg[pbase + NN] = 0.f;
        }
    } else {
        for (int i = tid; i < NN; i += 1024) {
            SKg[b * NN + i]  = sKey[i];
            PERM[b * NN + i] = sIdx[i];
        }
        for (int i = tid; i < NN; i += 1024) {
            float tau = -f1b[i];
            int lo = 0, hi = NN;
            while (lo < hi) { int m = (lo + hi) >> 1; if (sKey[m] <= tau) lo = m + 1; else hi = m; }
            KIDX[b * NN + i] = lo;
        }
    }
}

// ---------------------------------------------------------------------------
// K3 (fused k_uw + k_chunk + k_offsets + k_prefix): single-pass vector prefix
// sums via decoupled lookback. Grid = BB*CH blocks (b*CH + c), 256 threads.
// Per block: compute u/w for its CL positions inline (binary search on SF1 in
// LDS), gather Wh once, keep products in LDS, publish chunk totals, lookback
// for the running offset, then write the PU/PW prefix rows.
// ---------------------------------------------------------------------------
__global__ __launch_bounds__(256) void k_scan(const float* __restrict__ Wh,
                                              const float* __restrict__ SF1g,
                                              const float* __restrict__ PAg,
                                              const float* __restrict__ SAg,
                                              const float* __restrict__ SKg,
                                              const int* __restrict__ PERM,
                                              float* __restrict__ AGGU,
                                              float* __restrict__ AGGW,
                                              float* __restrict__ INCU,
                                              float* __restrict__ INCW,
                                              int* __restrict__ FLAG,
                                              float* __restrict__ PU,
                                              float* __restrict__ PW) {
    __shared__ float sSF1[NN];          // 8 KB
    __shared__ float prodU[CL][FF];     // 32 KB
    __shared__ float prodW[CL][FF];     // 32 KB
    __shared__ float sU[CL], sW[CL];
    __shared__ int   sJ[CL];
    __shared__ float redU[2][FF], redW[2][FF];

    const int blk  = blockIdx.x;        // b*CH + c
    const int b    = blk / CH, c = blk % CH;
    const int tid  = threadIdx.x;
    const int f    = tid & 127;
    const int half = tid >> 7;
    const int base = b * NN + c * CL;
    const size_t pbase = (size_t)b * (NN + 1);

    for (int i = tid; i < NN; i += 256) sSF1[i] = SF1g[b * NN + i];
    if (tid >= 64 && tid < 64 + CL) sJ[tid - 64] = PERM[base + tid - 64];
    __syncthreads();

    if (tid < CL) {   // wave 0: per-t softmax denominator -> u,w
        int t = tid;
        float f2v = SKg[base + t];
        float tau = -f2v;
        int lo = 0, hi = NN;
        while (lo < hi) { int m = (lo + hi) >> 1; if (sSF1[m] <= tau) lo = m + 1; else hi = m; }
        float eS = expf(NEG * f2v);
        float eF = expf(f2v);
        float inv = 1.0f / (eS * PAg[pbase + lo] + eF * SAg[pbase + lo]);
        sU[t] = eF * inv;
        sW[t] = eS * inv;
    }
    __syncthreads();

    // gather pass: products into LDS, per-thread partial totals
    const float* Whb = Wh + (size_t)b * NN * FF;
    float tU = 0.f, tW = 0.f;
#pragma unroll 4
    for (int tt = 0; tt < CL / 2; ++tt) {
        int t = tt * 2 + half;
        float whv = Whb[(size_t)sJ[t] * FF + f];
        float pu = sU[t] * whv, pw = sW[t] * whv;
        prodU[t][f] = pu; prodW[t][f] = pw;
        tU += pu; tW += pw;
    }
    redU[half][f] = tU; redW[half][f] = tW;
    __syncthreads();
    float totU = redU[0][f] + redU[1][f];
    float totW = redW[0][f] + redW[1][f];

    // publish aggregate (or inclusive if first chunk)
    if (c == 0) {
        if (half == 0) __hip_atomic_store(&INCU[(size_t)blk * FF + f], totU, __ATOMIC_RELAXED, __HIP_MEMORY_SCOPE_AGENT);
        else           __hip_atomic_store(&INCW[(size_t)blk * FF + f], totW, __ATOMIC_RELAXED, __HIP_MEMORY_SCOPE_AGENT);
        __syncthreads();
        if (tid == 0) { __threadfence(); __hip_atomic_store(&FLAG[blk], 2, __ATOMIC_RELEASE, __HIP_MEMORY_SCOPE_AGENT); }
    } else {
        if (half == 0) __hip_atomic_store(&AGGU[(size_t)blk * FF + f], totU, __ATOMIC_RELAXED, __HIP_MEMORY_SCOPE_AGENT);
        else           __hip_atomic_store(&AGGW[(size_t)blk * FF + f], totW, __ATOMIC_RELAXED, __HIP_MEMORY_SCOPE_AGENT);
        __syncthreads();
        if (tid == 0) { __threadfence(); __hip_atomic_store(&FLAG[blk], 1, __ATOMIC_RELEASE, __HIP_MEMORY_SCOPE_AGENT); }
    }

    // decoupled lookback (only waits on lower-indexed blocks)
    float offU = 0.f, offW = 0.f;
    if (c != 0) {
        int p = blk - 1;
        while (true) {
            int fl;
            do { fl = __hip_atomic_load(&FLAG[p], __ATOMIC_ACQUIRE, __HIP_MEMORY_SCOPE_AGENT); } while (fl == 0);
            if (fl == 2) {
                offU += __hip_atomic_load(&INCU[(size_t)p * FF + f], __ATOMIC_RELAXED, __HIP_MEMORY_SCOPE_AGENT);
                offW += __hip_atomic_load(&INCW[(size_t)p * FF + f], __ATOMIC_RELAXED, __HIP_MEMORY_SCOPE_AGENT);
                break;
            } else {
                offU += __hip_atomic_load(&AGGU[(size_t)p * FF + f], __ATOMIC_RELAXED, __HIP_MEMORY_SCOPE_AGENT);
                offW += __hip_atomic_load(&AGGW[(size_t)p * FF + f], __ATOMIC_RELAXED, __HIP_MEMORY_SCOPE_AGENT);
                p--;
            }
        }
        // publish inclusive ASAP for successors
        if (half == 0) __hip_atomic_store(&INCU[(size_t)blk * FF + f], offU + totU, __ATOMIC_RELAXED, __HIP_MEMORY_SCOPE_AGENT);
        else           __hip_atomic_store(&INCW[(size_t)blk * FF + f], offW + totW, __ATOMIC_RELAXED, __HIP_MEMORY_SCOPE_AGENT);
        __syncthreads();
        if (tid == 0) { __threadfence(); __hip_atomic_store(&FLAG[blk], 2, __ATOMIC_RELEASE, __HIP_MEMORY_SCOPE_AGENT); }
    }

    // write exclusive prefix rows; half 0 -> PU, half 1 -> PW
    if (half == 0) {
        float aU = offU;
#pragma unroll 4
        for (int t = 0; t < CL; ++t) {
            int g = c * CL + t;
            PU[(pbase + g) * FF + f] = aU;
            aU += prodU[t][f];
        }
        if (c == CH - 1) PU[(pbase + NN) * FF + f] = aU;
    } else {
        float aW = offW;
#pragma unroll 4
        for (int t = 0; t < CL; ++t) {
            int g = c * CL + t;
            PW[(pbase + g) * FF + f] = aW;
            aW += prodW[t][f];
        }
        if (c == CH - 1) PW[(pbase + NN) * FF + f] = aW;
    }
}

// ---------------------------------------------------------------------------
// K4: out[b,i,f] = e^{0.01 f1i} * PW[k_i] + e^{f1i} * (TotU - PU[k_i])
// ---------------------------------------------------------------------------
__global__ __launch_bounds__(256) void k_out(const float* __restrict__ PU,
                                             const float* __restrict__ PW,
                                             const float* __restrict__ f1,
                                             const int* __restrict__ KIDX,
                                             float* __restrict__ out) {
    int rowId = blockIdx.x * 2 + (threadIdx.x >> 7);
    int f = threadIdx.x & 127;
    int b = rowId >> 11;
    int k = KIDX[rowId];
    float f1v = f1[rowId];
    float alpha = expf(NEG * f1v);
    float beta  = expf(f1v);
    size_t rowB = (size_t)b * (NN + 1);
    float totU = PU[(rowB + NN) * FF + f];
    float pu   = PU[(rowB + k) * FF + f];
    float pw   = PW[(rowB + k) * FF + f];
    out[(size_t)rowId * FF + f] = alpha * pw + beta * (totU - pu);
}

// ---------------------------------------------------------------------------
extern "C" void kernel_launch(void* const* d_in, const int* in_sizes, int n_in,
                              void* d_out, int out_size, void* d_ws, size_t ws_size,
                              hipStream_t stream) {
    const float* h  = (const float*)d_in[0];
    // d_in[1] = adj — unused by the reference; never read.
    const float* W  = (const float*)d_in[2];
    const float* a  = (const float*)d_in[3];
    float* out = (float*)d_out;

    float* ws = (float*)d_ws;
    float* Wh   = ws;  ws += (size_t)BB * NN * FF;         // 4,194,304
    float* f1   = ws;  ws += BB * NN;
    float* f2   = ws;  ws += BB * NN;
    float* SF1  = ws;  ws += BB * NN;
    float* PA   = ws;  ws += BB * (NN + 1);
    float* SA   = ws;  ws += BB * (NN + 1);
    float* SK   = ws;  ws += BB * NN;
    float* AGGU = ws;  ws += BB * CH * FF;
    float* AGGW = ws;  ws += BB * CH * FF;
    float* INCU = ws;  ws += BB * CH * FF;
    float* INCW = ws;  ws += BB * CH * FF;
    float* PU   = ws;  ws += (size_t)BB * (NN + 1) * FF;   // 4,196,352
    float* PW   = ws;  ws += (size_t)BB * (NN + 1) * FF;
    int* PERM = (int*)ws;  ws += BB * NN;
    int* KIDX = (int*)ws;  ws += BB * NN;
    int* FLAG = (int*)ws;  // BB*CH ints

    hipMemsetAsync(FLAG, 0, BB * CH * sizeof(int), stream);
    k_wh   <<<(BB * NN) / 32, 256, 0, stream>>>(h, W, a, Wh, f1, f2);
    k_sort2<<<2 * BB, 1024, 0, stream>>>(f1, f2, SF1, PA, SA, SK, PERM, KIDX);
    k_scan <<<BB * CH, 256, 0, stream>>>(Wh, SF1, PA, SA, SK, PERM,
                                         AGGU, AGGW, INCU, INCW, FLAG, PU, PW);
    k_out  <<<(BB * NN) / 2, 256, 0, stream>>>(PU, PW, f1, KIDX, out);
}

// Round 4
// 402.233 us; speedup vs baseline: 1.3758x; 1.3758x over previous
//
#include <hip/hip_runtime.h>

#define BB 16
#define NN 2048
#define FF 128
#define NEG 0.01f
#define CH 32          // chunks per batch
#define CL (NN / CH)   // chunk length = 64

// ---------------------------------------------------------------------------
// K1: Wh = h @ W  (fp32, LDS-tiled), fused f1 = Wh·a1, f2 = Wh·a2
// ---------------------------------------------------------------------------
__global__ __launch_bounds__(256) void k_wh(const float* __restrict__ h,
                                            const float* __restrict__ Wg,
                                            const float* __restrict__ a,
                                            float* __restrict__ Wh,
                                            float* __restrict__ f1,
                                            float* __restrict__ f2) {
    __shared__ float Ws[64 * 128];   // [k][f] half-K tile (32 KB)
    __shared__ float hsT[64 * 36];   // [k][row] transposed h tile, pad 36

    const int tid  = threadIdx.x;
    const int fg   = tid & 31;
    const int slot = tid >> 5;
    const int f4   = fg * 4;
    const int rowBase = blockIdx.x * 32;

    float acc[4][4];
#pragma unroll
    for (int r = 0; r < 4; ++r)
#pragma unroll
        for (int c = 0; c < 4; ++c) acc[r][c] = 0.f;

    const float4* Wg4 = (const float4*)Wg;
    const float4* hg4 = (const float4*)h;

    for (int kh = 0; kh < 128; kh += 64) {
        __syncthreads();
        for (int idx = tid; idx < 64 * 32; idx += 256) {
            int kk = idx >> 5, ff = idx & 31;
            ((float4*)Ws)[kk * 32 + ff] = Wg4[(size_t)(kh + kk) * 32 + ff];
        }
#pragma unroll
        for (int pass = 0; pass < 2; ++pass) {
            int idx = pass * 256 + tid;
            int kq = idx & 15, row = idx >> 4;
            float4 h4 = hg4[(size_t)(rowBase + row) * 32 + (kh >> 2) + kq];
            hsT[(kq * 4 + 0) * 36 + row] = h4.x;
            hsT[(kq * 4 + 1) * 36 + row] = h4.y;
            hsT[(kq * 4 + 2) * 36 + row] = h4.z;
            hsT[(kq * 4 + 3) * 36 + row] = h4.w;
        }
        __syncthreads();
#pragma unroll 8
        for (int kk = 0; kk < 64; ++kk) {
            float4 wv = *(const float4*)&Ws[kk * 128 + f4];
            float4 hv = *(const float4*)&hsT[kk * 36 + slot * 4];
            acc[0][0] += hv.x * wv.x; acc[0][1] += hv.x * wv.y; acc[0][2] += hv.x * wv.z; acc[0][3] += hv.x * wv.w;
            acc[1][0] += hv.y * wv.x; acc[1][1] += hv.y * wv.y; acc[1][2] += hv.y * wv.z; acc[1][3] += hv.y * wv.w;
            acc[2][0] += hv.z * wv.x; acc[2][1] += hv.z * wv.y; acc[2][2] += hv.z * wv.z; acc[2][3] += hv.z * wv.w;
            acc[3][0] += hv.w * wv.x; acc[3][1] += hv.w * wv.y; acc[3][2] += hv.w * wv.z; acc[3][3] += hv.w * wv.w;
        }
    }

    const float4* ag4 = (const float4*)a;
    float4 a1v = ag4[fg];
    float4 a2v = ag4[32 + fg];

#pragma unroll
    for (int r = 0; r < 4; ++r) {
        int row = rowBase + slot * 4 + r;
        float4 o; o.x = acc[r][0]; o.y = acc[r][1]; o.z = acc[r][2]; o.w = acc[r][3];
        *(float4*)&Wh[(size_t)row * 128 + f4] = o;
        float p1 = acc[r][0] * a1v.x + acc[r][1] * a1v.y + acc[r][2] * a1v.z + acc[r][3] * a1v.w;
        float p2 = acc[r][0] * a2v.x + acc[r][1] * a2v.y + acc[r][2] * a2v.z + acc[r][3] * a2v.w;
#pragma unroll
        for (int m = 16; m >= 1; m >>= 1) {
            p1 += __shfl_xor(p1, m);
            p2 += __shfl_xor(p2, m);
        }
        if (fg == 0) { f1[row] = p1; f2[row] = p2; }
    }
}

// ---------------------------------------------------------------------------
__device__ __forceinline__ float wave_incl_scan(float s, int lane) {
#pragma unroll
    for (int m = 1; m <= 32; m <<= 1) {
        float o = __shfl_up(s, m);
        if (lane >= m) s += o;
    }
    return s;
}

#define WAVE_SYNC() do { __builtin_amdgcn_wave_barrier(); asm volatile("" ::: "memory"); } while (0)

// ---------------------------------------------------------------------------
// K2: 32 blocks x 1024 threads. Both tasks sort (key, idx) pairs ascending.
//  task 0: key=f1 -> SF1g, PERM1; shuffle scans -> PAg (excl prefix of
//          exp(0.01*sf1), N+1), SAg (suffix of exp(sf1), N+1).
//  task 1: key=f2 -> SKg, PERM2; KIDX[i] = #{t : sf2[t] <= -f1[i]}.
// Bitonic phases with j<=64 are wave-local; barrier only for j>=128 edges.
// ---------------------------------------------------------------------------
__global__ __launch_bounds__(1024) void k_sort2(const float* __restrict__ f1,
                                                const float* __restrict__ f2,
                                                float* __restrict__ SF1g,
                                                int* __restrict__ PERM1,
                                                float* __restrict__ PAg,
                                                float* __restrict__ SAg,
                                                float* __restrict__ SKg,
                                                int* __restrict__ PERM2,
                                                int* __restrict__ KIDX) {
    __shared__ float sKey[NN];
    __shared__ int   sIdx[NN];
    __shared__ float wtot[16];

    const int tid  = threadIdx.x;
    const int lane = tid & 63;
    const int w    = tid >> 6;
    const int b    = blockIdx.x & 15;
    const int task = blockIdx.x >> 4;

    const float* f1b = f1 + b * NN;
    const float* f2b = f2 + b * NN;
    const float* src = (task == 0) ? f1b : f2b;

    for (int i = tid; i < NN; i += 1024) { sKey[i] = src[i]; sIdx[i] = i; }

    int prevj = 1024;
    for (int k = 2; k <= NN; k <<= 1) {
        for (int j = k >> 1; j > 0; j >>= 1) {
            if (j >= 128 || prevj >= 128) __syncthreads();
            else WAVE_SYNC();
            int mask = j - 1;
            int i   = ((tid & ~mask) << 1) | (tid & mask);
            int ixj = i | j;
            bool up = ((i & k) == 0);
            float av = sKey[i], bv = sKey[ixj];
            if ((av > bv) == up) {
                sKey[i] = bv; sKey[ixj] = av;
                int t2 = sIdx[i]; sIdx[i] = sIdx[ixj]; sIdx[ixj] = t2;
            }
            prevj = j;
        }
    }
    __syncthreads();

    if (task == 0) {
        for (int i = tid; i < NN; i += 1024) {
            SF1g[b * NN + i]  = sKey[i];
            PERM1[b * NN + i] = sIdx[i];
        }
        const size_t pbase = (size_t)b * (NN + 1);
        {
            float a0 = expf(NEG * sKey[2 * tid]);
            float a1 = expf(NEG * sKey[2 * tid + 1]);
            float s = a0 + a1;
            float v = wave_incl_scan(s, lane);
            if (lane == 63) wtot[w] = v;
            __syncthreads();
            float off = 0.f;
#pragma unroll
            for (int ww = 0; ww < 16; ++ww) off += (ww < w) ? wtot[ww] : 0.f;
            float excl = off + v - s;
            PAg[pbase + 2 * tid]     = excl;
            PAg[pbase + 2 * tid + 1] = excl + a0;
            if (tid == 1023) PAg[pbase + NN] = off + v;
        }
        __syncthreads();
        {
            float y0 = expf(sKey[NN - 1 - 2 * tid]);
            float y1 = expf(sKey[NN - 2 - 2 * tid]);
            float s = y0 + y1;
            float v = wave_incl_scan(s, lane);
            if (lane == 63) wtot[w] = v;
            __syncthreads();
            float off = 0.f;
#pragma unroll
            for (int ww = 0; ww < 16; ++ww) off += (ww < w) ? wtot[ww] : 0.f;
            SAg[pbase + NN - 1 - 2 * tid] = off + (v - s) + y0;
            SAg[pbase + NN - 2 - 2 * tid] = off + v;
            if (tid == 0) SAg[pbase + NN] = 0.f;
        }
    } else {
        for (int i = tid; i < NN; i += 1024) {
            SKg[b * NN + i]   = sKey[i];
            PERM2[b * NN + i] = sIdx[i];
        }
        for (int i = tid; i < NN; i += 1024) {
            float tau = -f1b[i];
            int lo = 0, hi = NN;
            while (lo < hi) { int m = (lo + hi) >> 1; if (sKey[m] <= tau) lo = m + 1; else hi = m; }
            KIDX[b * NN + i] = lo;
        }
    }
}

// ---------------------------------------------------------------------------
// K3 (k_uw + k_chunk fused): per (b,c) block of 128 threads.
// Compute u_j = e^{f2}/D_j, w_j = e^{0.01 f2}/D_j for the chunk's 64 t's
// (binary search on LDS-cached SF1), write Uarr/Warr, then gather Wh rows and
// serially accumulate the chunk totals CU/CW.
// ---------------------------------------------------------------------------
__global__ __launch_bounds__(128) void k_uwchunk(const float* __restrict__ Wh,
                                                 const float* __restrict__ SF1g,
                                                 const float* __restrict__ PAg,
                                                 const float* __restrict__ SAg,
                                                 const float* __restrict__ SKg,
                                                 const int* __restrict__ PERM2,
                                                 float* __restrict__ Uarr,
                                                 float* __restrict__ Warr,
                                                 float* __restrict__ CU,
                                                 float* __restrict__ CW) {
    __shared__ float sSF1[NN];
    __shared__ float sU[CL], sW[CL];
    __shared__ int   sJ[CL];
    const int blk = blockIdx.x;
    const int b = blk / CH, c = blk % CH;
    const int f = threadIdx.x;
    const int base = b * NN + c * CL;
    const size_t pbase = (size_t)b * (NN + 1);

    for (int i = f; i < NN; i += 128) sSF1[i] = SF1g[b * NN + i];
    if (f < CL) sJ[f] = PERM2[base + f];
    __syncthreads();

    if (f < CL) {
        float f2v = SKg[base + f];
        float tau = -f2v;
        int lo = 0, hi = NN;
        while (lo < hi) { int m = (lo + hi) >> 1; if (sSF1[m] <= tau) lo = m + 1; else hi = m; }
        float eS = expf(NEG * f2v);
        float eF = expf(f2v);
        float inv = 1.0f / (eS * PAg[pbase + lo] + eF * SAg[pbase + lo]);
        float u = eF * inv, wv = eS * inv;
        sU[f] = u; sW[f] = wv;
        Uarr[base + f] = u; Warr[base + f] = wv;
    }
    __syncthreads();

    const float* Whb = Wh + (size_t)b * NN * FF;
    float aU = 0.f, aW = 0.f;
#pragma unroll 8
    for (int t = 0; t < CL; ++t) {
        float whv = Whb[(size_t)sJ[t] * FF + f];
        aU += sU[t] * whv;
        aW += sW[t] * whv;
    }
    CU[(size_t)blk * FF + f] = aU;
    CW[(size_t)blk * FF + f] = aW;
}

// ---------------------------------------------------------------------------
// K4: exclusive scan of chunk totals (in place), grand total TOTU, and
// KS[pos] = KIDX[PERM1[pos]] (cut index in f1-sorted order; non-increasing).
// ---------------------------------------------------------------------------
__global__ __launch_bounds__(128) void k_offsets(float* __restrict__ CU,
                                                 float* __restrict__ CW,
                                                 float* __restrict__ TOTU,
                                                 const int* __restrict__ KIDX,
                                                 const int* __restrict__ PERM1,
                                                 int* __restrict__ KS) {
    const int b = blockIdx.x, f = threadIdx.x;
    float aU = 0.f, aW = 0.f;
#pragma unroll
    for (int c = 0; c < CH; ++c) {
        size_t idx = (size_t)(b * CH + c) * FF + f;
        float tU = CU[idx], tW = CW[idx];
        CU[idx] = aU; CW[idx] = aW;
        aU += tU; aW += tW;
    }
    TOTU[b * FF + f] = aU;
    for (int pos = f; pos < NN; pos += 128)
        KS[b * NN + pos] = KIDX[b * NN + PERM1[b * NN + pos]];
}

// ---------------------------------------------------------------------------
// K5 (k_prefix + k_out fused): per (b,c) block of 128 threads.
// Rows whose cut k_i falls in chunk c form a contiguous segment of the
// f1-sorted order (KS non-increasing). Two-pointer sweep: advance the running
// register prefix (aU,aW) through the chunk's products as k increases, and
// emit out rows directly. No PU/PW materialization.
// ---------------------------------------------------------------------------
__global__ __launch_bounds__(128) void k_outfused(const float* __restrict__ Wh,
                                                  const float* __restrict__ Uarr,
                                                  const float* __restrict__ Warr,
                                                  const int* __restrict__ PERM2,
                                                  const float* __restrict__ CU,
                                                  const float* __restrict__ CW,
                                                  const float* __restrict__ TOTU,
                                                  const int* __restrict__ KS,
                                                  const int* __restrict__ PERM1,
                                                  const float* __restrict__ SF1g,
                                                  float* __restrict__ out) {
    __shared__ float whv[CL][FF];          // 32 KB
    __shared__ float sU[CL], sW[CL];
    __shared__ int   sJ[CL];
    __shared__ int   sP[128];
    __shared__ float sF[128];
    __shared__ int   sK[128];

    const int blk = blockIdx.x;
    const int b = blk / CH, c = blk % CH;
    const int f = threadIdx.x;
    const int base = b * NN + c * CL;
    const int* KSb = KS + b * NN;
    const int lowv = CL * c;
    const int upper = (c == CH - 1) ? (NN + 1) : CL * (c + 1);

    // segment [segLo, segHi): rows with lowv <= KS < upper (KS non-increasing)
    int lo = 0, hi = NN;
    while (lo < hi) { int m = (lo + hi) >> 1; if (KSb[m] < upper) hi = m; else lo = m + 1; }
    const int segLo = lo;
    lo = 0; hi = NN;
    while (lo < hi) { int m = (lo + hi) >> 1; if (KSb[m] < lowv) hi = m; else lo = m + 1; }
    const int segHi = lo;

    if (f < CL) {
        sU[f] = Uarr[base + f];
        sW[f] = Warr[base + f];
        sJ[f] = PERM2[base + f];
    }
    __syncthreads();

    const float* Whb = Wh + (size_t)b * NN * FF;
#pragma unroll 8
    for (int t = 0; t < CL; ++t) whv[t][f] = Whb[(size_t)sJ[t] * FF + f];

    float aU = CU[(size_t)blk * FF + f];
    float aW = CW[(size_t)blk * FF + f];
    const float totU = TOTU[b * FF + f];
    float* outb = out + (size_t)b * NN * FF;

    int t = 0;
    for (int start = segHi; start > segLo; ) {
        int cnt = start - segLo; if (cnt > 128) cnt = 128;
        int s0 = start - cnt;
        __syncthreads();
        if (f < cnt) {
            int p = s0 + f;
            sP[f] = PERM1[b * NN + p];
            sF[f] = SF1g[b * NN + p];
            sK[f] = KSb[p];
        }
        __syncthreads();
        for (int q = cnt - 1; q >= 0; --q) {         // pos descending -> k ascending
            int r = sK[q] - lowv;
            while (t < r) { aU += sU[t] * whv[t][f]; aW += sW[t] * whv[t][f]; ++t; }
            float f1v = sF[q];
            outb[(size_t)sP[q] * FF + f] = expf(NEG * f1v) * aW + expf(f1v) * (totU - aU);
        }
        start = s0;
    }
}

// ---------------------------------------------------------------------------
extern "C" void kernel_launch(void* const* d_in, const int* in_sizes, int n_in,
                              void* d_out, int out_size, void* d_ws, size_t ws_size,
                              hipStream_t stream) {
    const float* h  = (const float*)d_in[0];
    // d_in[1] = adj — unused by the reference; never read.
    const float* W  = (const float*)d_in[2];
    const float* a  = (const float*)d_in[3];
    float* out = (float*)d_out;

    float* ws = (float*)d_ws;
    float* Wh   = ws;  ws += (size_t)BB * NN * FF;     // 16 MB
    float* f1   = ws;  ws += BB * NN;
    float* f2   = ws;  ws += BB * NN;
    float* SF1  = ws;  ws += BB * NN;
    float* PA   = ws;  ws += BB * (NN + 1);
    float* SA   = ws;  ws += BB * (NN + 1);
    float* SK   = ws;  ws += BB * NN;
    float* Uarr = ws;  ws += BB * NN;
    float* Warr = ws;  ws += BB * NN;
    float* CU   = ws;  ws += BB * CH * FF;
    float* CW   = ws;  ws += BB * CH * FF;
    float* TOTU = ws;  ws += BB * FF;
    int* PERM1 = (int*)ws;  ws += BB * NN;
    int* PERM2 = (int*)ws;  ws += BB * NN;
    int* KIDX  = (int*)ws;  ws += BB * NN;
    int* KS    = (int*)ws;  // ~19 MB total

    k_wh      <<<(BB * NN) / 32, 256, 0, stream>>>(h, W, a, Wh, f1, f2);
    k_sort2   <<<2 * BB, 1024, 0, stream>>>(f1, f2, SF1, PERM1, PA, SA, SK, PERM2, KIDX);
    k_uwchunk <<<BB * CH, 128, 0, stream>>>(Wh, SF1, PA, SA, SK, PERM2, Uarr, Warr, CU, CW);
    k_offsets <<<BB, 128, 0, stream>>>(CU, CW, TOTU, KIDX, PERM1, KS);
    k_outfused<<<BB * CH, 128, 0, stream>>>(Wh, Uarr, Warr, PERM2, CU, CW, TOTU, KS, PERM1, SF1, out);
}